// Round 1
// baseline (518.551 us; speedup 1.0000x reference)
//
#include <hip/hip_runtime.h>
#include <hip/hip_bf16.h>

#define NN 131072
#define DD 512
#define CC 1000

// ws layout (floats):
//       0 : w          [CC*DD]   normalized classifier
//  512000 : sqw        [CC]      sum(w*w) per row
//  513000 : class_sum  [CC]
//  514000 : class_cnt  [CC]
//  515000 : pair_acc   [2]       {sum of 1/d2, mask count}

__device__ __forceinline__ float wave_reduce(float v) {
#pragma unroll
    for (int m = 32; m > 0; m >>= 1) v += __shfl_xor(v, m, 64);
    return v;
}

// --- normalize classifier rows: one wave per row ---
__global__ __launch_bounds__(64) void knorm(const float* __restrict__ cls,
                                            float* __restrict__ w,
                                            float* __restrict__ sqw) {
    int c = blockIdx.x;
    int lane = threadIdx.x;
    const float4* src = (const float4*)(cls + (size_t)c * DD) + lane * 2;
    float4 f0 = src[0], f1 = src[1];
    float s = f0.x * f0.x + f0.y * f0.y + f0.z * f0.z + f0.w * f0.w +
              f1.x * f1.x + f1.y * f1.y + f1.z * f1.z + f1.w * f1.w;
    s = wave_reduce(s);
    float inv = rsqrtf(s);
    float4 w0 = make_float4(f0.x * inv, f0.y * inv, f0.z * inv, f0.w * inv);
    float4 w1 = make_float4(f1.x * inv, f1.y * inv, f1.z * inv, f1.w * inv);
    float q = w0.x * w0.x + w0.y * w0.y + w0.z * w0.z + w0.w * w0.w +
              w1.x * w1.x + w1.y * w1.y + w1.z * w1.z + w1.w * w1.w;
    q = wave_reduce(q);
    float4* dst = (float4*)(w + (size_t)c * DD) + lane * 2;
    dst[0] = w0;
    dst[1] = w1;
    if (lane == 0) sqw[c] = q;
}

// --- pairwise weight term: 32x32 tile per block, 2x2 per thread ---
#define TILE 32
#define KC 64
__global__ __launch_bounds__(256) void kpair(const float* __restrict__ w,
                                             const float* __restrict__ sqw,
                                             float* __restrict__ pair_acc) {
    int bi = blockIdx.y, bj = blockIdx.x;
    if (bj < bi) return;  // upper-triangular tiles only

    __shared__ float As[TILE][KC + 1];
    __shared__ float Bs[TILE][KC + 1];

    int tid = threadIdx.x;
    int tx = tid & 15, ty = tid >> 4;
    int lrow = tid >> 3;         // 0..31
    int lcol = (tid & 7) * 8;    // 0,8,..,56
    int i0 = bi * TILE, j0 = bj * TILE;

    float acc00 = 0.f, acc01 = 0.f, acc10 = 0.f, acc11 = 0.f;

    for (int k0 = 0; k0 < DD; k0 += KC) {
        {
            int gi = i0 + lrow;
            float4 v0 = make_float4(0, 0, 0, 0), v1 = v0;
            if (gi < CC) {
                const float4* p = (const float4*)(w + (size_t)gi * DD + k0 + lcol);
                v0 = p[0]; v1 = p[1];
            }
            As[lrow][lcol + 0] = v0.x; As[lrow][lcol + 1] = v0.y;
            As[lrow][lcol + 2] = v0.z; As[lrow][lcol + 3] = v0.w;
            As[lrow][lcol + 4] = v1.x; As[lrow][lcol + 5] = v1.y;
            As[lrow][lcol + 6] = v1.z; As[lrow][lcol + 7] = v1.w;

            int gj = j0 + lrow;
            v0 = make_float4(0, 0, 0, 0); v1 = v0;
            if (gj < CC) {
                const float4* p = (const float4*)(w + (size_t)gj * DD + k0 + lcol);
                v0 = p[0]; v1 = p[1];
            }
            Bs[lrow][lcol + 0] = v0.x; Bs[lrow][lcol + 1] = v0.y;
            Bs[lrow][lcol + 2] = v0.z; Bs[lrow][lcol + 3] = v0.w;
            Bs[lrow][lcol + 4] = v1.x; Bs[lrow][lcol + 5] = v1.y;
            Bs[lrow][lcol + 6] = v1.z; Bs[lrow][lcol + 7] = v1.w;
        }
        __syncthreads();
#pragma unroll
        for (int k = 0; k < KC; ++k) {
            float a0 = As[2 * ty + 0][k];
            float a1 = As[2 * ty + 1][k];
            float b0 = Bs[2 * tx + 0][k];
            float b1 = Bs[2 * tx + 1][k];
            acc00 += a0 * b0; acc01 += a0 * b1;
            acc10 += a1 * b0; acc11 += a1 * b1;
        }
        __syncthreads();
    }

    float lsum = 0.f, lcnt = 0.f;
    int i_ = i0 + 2 * ty, j_ = j0 + 2 * tx;
    {
        int ii[2] = {i_, i_ + 1};
        int jj[2] = {j_, j_ + 1};
        float d[2][2] = {{acc00, acc01}, {acc10, acc11}};
#pragma unroll
        for (int a = 0; a < 2; ++a)
#pragma unroll
            for (int b = 0; b < 2; ++b) {
                int i = ii[a], j = jj[b];
                if (i < CC && j < CC && j > i) {
                    float d2 = sqw[i] + sqw[j] - 2.f * d[a][b];
                    if (d2 > 0.f) { lsum += 1.f / d2; lcnt += 1.f; }
                }
            }
    }
    lsum = wave_reduce(lsum);
    lcnt = wave_reduce(lcnt);
    __shared__ float rs[4], rc[4];
    int wv = tid >> 6;
    if ((tid & 63) == 0) { rs[wv] = lsum; rc[wv] = lcnt; }
    __syncthreads();
    if (tid == 0) {
        atomicAdd(pair_acc + 0, rs[0] + rs[1] + rs[2] + rs[3]);
        atomicAdd(pair_acc + 1, rc[0] + rc[1] + rc[2] + rc[3]);
    }
}

// --- sample term + fused feat passthrough: one wave per sample row ---
__global__ __launch_bounds__(256) void ksample(const float* __restrict__ feat,
                                               const int* __restrict__ target,
                                               const float* __restrict__ w,
                                               const float* __restrict__ sqw,
                                               float* __restrict__ class_sum,
                                               float* __restrict__ class_cnt,
                                               float* __restrict__ out_feat) {
    int n = (blockIdx.x << 2) + (threadIdx.x >> 6);
    int lane = threadIdx.x & 63;
    size_t base = (size_t)n * DD + lane * 8;

    const float4* fp = (const float4*)(feat + base);
    float4 f0 = fp[0], f1 = fp[1];

    // passthrough copy (dest only 8B-aligned: out + 2 floats)
    float2* op = (float2*)(out_feat + base);
    op[0] = make_float2(f0.x, f0.y);
    op[1] = make_float2(f0.z, f0.w);
    op[2] = make_float2(f1.x, f1.y);
    op[3] = make_float2(f1.z, f1.w);

    int t = target[n];
    const float4* wp = (const float4*)(w + (size_t)t * DD + lane * 8);
    float4 w0 = wp[0], w1 = wp[1];

    float sff = f0.x * f0.x + f0.y * f0.y + f0.z * f0.z + f0.w * f0.w +
                f1.x * f1.x + f1.y * f1.y + f1.z * f1.z + f1.w * f1.w;
    float sfw = f0.x * w0.x + f0.y * w0.y + f0.z * w0.z + f0.w * w0.w +
                f1.x * w1.x + f1.y * w1.y + f1.z * w1.z + f1.w * w1.w;
#pragma unroll
    for (int m = 32; m > 0; m >>= 1) {
        sff += __shfl_xor(sff, m, 64);
        sfw += __shfl_xor(sfw, m, 64);
    }
    if (lane == 0) {
        float inv = rsqrtf(sff);
        float d2 = sff * inv * inv + sqw[t] - 2.f * inv * sfw;
        d2 = fmaxf(d2, 0.f);
        float dist = sqrtf(d2);
        atomicAdd(class_sum + t, dist);
        atomicAdd(class_cnt + t, 1.f);
    }
}

// --- finalize both scalars ---
__global__ __launch_bounds__(256) void kfin(const float* __restrict__ class_sum,
                                            const float* __restrict__ class_cnt,
                                            const float* __restrict__ pair_acc,
                                            float* __restrict__ out) {
    float msum = 0.f, pcnt = 0.f;
    for (int c = threadIdx.x; c < CC; c += 256) {
        float cnt = class_cnt[c];
        if (cnt > 0.f) {
            msum += class_sum[c] / cnt;
            pcnt += 1.f;
        }
    }
    msum = wave_reduce(msum);
    pcnt = wave_reduce(pcnt);
    __shared__ float rs[4], rc[4];
    int wv = threadIdx.x >> 6;
    if ((threadIdx.x & 63) == 0) { rs[wv] = msum; rc[wv] = pcnt; }
    __syncthreads();
    if (threadIdx.x == 0) {
        float sm = rs[0] + rs[1] + rs[2] + rs[3];
        float sp = rc[0] + rc[1] + rc[2] + rc[3];
        out[0] = 1.0f * (sm / sp);                      // BETA * sample_wise
        out[1] = 1.0f * (pair_acc[0] / pair_acc[1]);    // ALPHA * weight_wise
    }
}

extern "C" void kernel_launch(void* const* d_in, const int* in_sizes, int n_in,
                              void* d_out, int out_size, void* d_ws, size_t ws_size,
                              hipStream_t stream) {
    const float* feat = (const float*)d_in[0];
    const float* cls = (const float*)d_in[1];
    const int* target = (const int*)d_in[2];
    float* out = (float*)d_out;
    float* ws = (float*)d_ws;

    float* w = ws;
    float* sqw = ws + 512000;
    float* class_sum = ws + 513000;
    float* class_cnt = ws + 514000;
    float* pair_acc = ws + 515000;

    // zero accumulators (class_sum, class_cnt, pair_acc are contiguous)
    hipMemsetAsync(class_sum, 0, (2 * CC + 2) * sizeof(float), stream);

    knorm<<<CC, 64, 0, stream>>>(cls, w, sqw);
    kpair<<<dim3((CC + TILE - 1) / TILE, (CC + TILE - 1) / TILE), 256, 0, stream>>>(w, sqw, pair_acc);
    ksample<<<NN / 4, 256, 0, stream>>>(feat, target, w, sqw, class_sum, class_cnt, out + 2);
    kfin<<<1, 256, 0, stream>>>(class_sum, class_cnt, pair_acc, out);
}

// Round 2
// 515.734 us; speedup vs baseline: 1.0055x; 1.0055x over previous
//
#include <hip/hip_runtime.h>
#include <hip/hip_bf16.h>

#define NN 131072
#define DD 512
#define CC 1000

// ws layout (floats):
//       0 : w          [CC*DD]   normalized classifier
//  512000 : sqw        [CC]      sum(w*w) per row
//  513000 : class_sum  [CC]
//  514000 : class_cnt  [CC]
//  515000 : pair_acc   [2]       {sum of 1/d2, mask count}

__device__ __forceinline__ float wave_reduce(float v) {
#pragma unroll
    for (int m = 32; m > 0; m >>= 1) v += __shfl_xor(v, m, 64);
    return v;
}

// --- normalize classifier rows: one wave per row ---
__global__ __launch_bounds__(64) void knorm(const float* __restrict__ cls,
                                            float* __restrict__ w,
                                            float* __restrict__ sqw) {
    int c = blockIdx.x;
    int lane = threadIdx.x;
    const float4* src = (const float4*)(cls + (size_t)c * DD) + lane * 2;
    float4 f0 = src[0], f1 = src[1];
    float s = f0.x * f0.x + f0.y * f0.y + f0.z * f0.z + f0.w * f0.w +
              f1.x * f1.x + f1.y * f1.y + f1.z * f1.z + f1.w * f1.w;
    s = wave_reduce(s);
    float inv = rsqrtf(s);
    float4 w0 = make_float4(f0.x * inv, f0.y * inv, f0.z * inv, f0.w * inv);
    float4 w1 = make_float4(f1.x * inv, f1.y * inv, f1.z * inv, f1.w * inv);
    float q = w0.x * w0.x + w0.y * w0.y + w0.z * w0.z + w0.w * w0.w +
              w1.x * w1.x + w1.y * w1.y + w1.z * w1.z + w1.w * w1.w;
    q = wave_reduce(q);
    float4* dst = (float4*)(w + (size_t)c * DD) + lane * 2;
    dst[0] = w0;
    dst[1] = w1;
    if (lane == 0) sqw[c] = q;
}

// --- pairwise weight term: 32x32 tile per block, 2x2 per thread ---
#define TILE 32
#define KC 64
__global__ __launch_bounds__(256) void kpair(const float* __restrict__ w,
                                             const float* __restrict__ sqw,
                                             float* __restrict__ pair_acc) {
    int bi = blockIdx.y, bj = blockIdx.x;
    if (bj < bi) return;  // upper-triangular tiles only

    __shared__ float As[TILE][KC + 1];
    __shared__ float Bs[TILE][KC + 1];

    int tid = threadIdx.x;
    int tx = tid & 15, ty = tid >> 4;
    int lrow = tid >> 3;         // 0..31
    int lcol = (tid & 7) * 8;    // 0,8,..,56
    int i0 = bi * TILE, j0 = bj * TILE;

    float acc00 = 0.f, acc01 = 0.f, acc10 = 0.f, acc11 = 0.f;

    for (int k0 = 0; k0 < DD; k0 += KC) {
        {
            int gi = i0 + lrow;
            float4 v0 = make_float4(0, 0, 0, 0), v1 = v0;
            if (gi < CC) {
                const float4* p = (const float4*)(w + (size_t)gi * DD + k0 + lcol);
                v0 = p[0]; v1 = p[1];
            }
            As[lrow][lcol + 0] = v0.x; As[lrow][lcol + 1] = v0.y;
            As[lrow][lcol + 2] = v0.z; As[lrow][lcol + 3] = v0.w;
            As[lrow][lcol + 4] = v1.x; As[lrow][lcol + 5] = v1.y;
            As[lrow][lcol + 6] = v1.z; As[lrow][lcol + 7] = v1.w;

            int gj = j0 + lrow;
            v0 = make_float4(0, 0, 0, 0); v1 = v0;
            if (gj < CC) {
                const float4* p = (const float4*)(w + (size_t)gj * DD + k0 + lcol);
                v0 = p[0]; v1 = p[1];
            }
            Bs[lrow][lcol + 0] = v0.x; Bs[lrow][lcol + 1] = v0.y;
            Bs[lrow][lcol + 2] = v0.z; Bs[lrow][lcol + 3] = v0.w;
            Bs[lrow][lcol + 4] = v1.x; Bs[lrow][lcol + 5] = v1.y;
            Bs[lrow][lcol + 6] = v1.z; Bs[lrow][lcol + 7] = v1.w;
        }
        __syncthreads();
#pragma unroll
        for (int k = 0; k < KC; ++k) {
            float a0 = As[2 * ty + 0][k];
            float a1 = As[2 * ty + 1][k];
            float b0 = Bs[2 * tx + 0][k];
            float b1 = Bs[2 * tx + 1][k];
            acc00 += a0 * b0; acc01 += a0 * b1;
            acc10 += a1 * b0; acc11 += a1 * b1;
        }
        __syncthreads();
    }

    float lsum = 0.f, lcnt = 0.f;
    int i_ = i0 + 2 * ty, j_ = j0 + 2 * tx;
    {
        int ii[2] = {i_, i_ + 1};
        int jj[2] = {j_, j_ + 1};
        float d[2][2] = {{acc00, acc01}, {acc10, acc11}};
#pragma unroll
        for (int a = 0; a < 2; ++a)
#pragma unroll
            for (int b = 0; b < 2; ++b) {
                int i = ii[a], j = jj[b];
                if (i < CC && j < CC && j > i) {
                    float d2 = sqw[i] + sqw[j] - 2.f * d[a][b];
                    if (d2 > 0.f) { lsum += 1.f / d2; lcnt += 1.f; }
                }
            }
    }
    lsum = wave_reduce(lsum);
    lcnt = wave_reduce(lcnt);
    __shared__ float rs[4], rc[4];
    int wv = tid >> 6;
    if ((tid & 63) == 0) { rs[wv] = lsum; rc[wv] = lcnt; }
    __syncthreads();
    if (tid == 0) {
        atomicAdd(pair_acc + 0, rs[0] + rs[1] + rs[2] + rs[3]);
        atomicAdd(pair_acc + 1, rc[0] + rc[1] + rc[2] + rc[3]);
    }
}

// --- sample term + fused feat passthrough ---
// One 256-thread block handles 2 rows (2*512 floats = 256 float4).
// Thread t owns float4 index t of the block's contiguous chunk:
//   - feat loads: 16B/lane fully coalesced (4KB contiguous per wave-pair)
//   - w loads: coalesced within each 128-thread row group (w lives in L2)
//   - passthrough stores: two adjacent float2 per thread (dest is 8B-aligned)
__global__ __launch_bounds__(256) void ksample(const float* __restrict__ feat,
                                               const int* __restrict__ target,
                                               const float* __restrict__ w,
                                               const float* __restrict__ sqw,
                                               float* __restrict__ class_sum,
                                               float* __restrict__ class_cnt,
                                               float* __restrict__ out_feat) {
    int t = threadIdx.x;
    int rlocal = t >> 7;                         // 0 or 1: which row in block
    long long n = (long long)blockIdx.x * 2 + rlocal;
    size_t f4idx = (size_t)blockIdx.x * 256 + t; // float4 index into feat

    const float4* f4 = (const float4*)feat;
    float4 f = f4[f4idx];

    int tgt = target[n];
    int col4 = t & 127;
    const float4* w4 = (const float4*)w;
    float4 wv = w4[(size_t)tgt * 128 + col4];

    // passthrough copy (dest out+2 is only 8B-aligned)
    float2* o2 = (float2*)out_feat;
    o2[2 * f4idx] = make_float2(f.x, f.y);
    o2[2 * f4idx + 1] = make_float2(f.z, f.w);

    float ff = f.x * f.x + f.y * f.y + f.z * f.z + f.w * f.w;
    float fw = f.x * wv.x + f.y * wv.y + f.z * wv.z + f.w * wv.w;
#pragma unroll
    for (int m = 32; m > 0; m >>= 1) {
        ff += __shfl_xor(ff, m, 64);
        fw += __shfl_xor(fw, m, 64);
    }

    __shared__ float red[4][2];
    int wid = t >> 6;
    if ((t & 63) == 0) { red[wid][0] = ff; red[wid][1] = fw; }
    __syncthreads();

    if ((t & 127) == 0) {  // threads 0 and 128 finalize rows 0 and 1
        int wa = rlocal * 2, wb = rlocal * 2 + 1;
        float sff = red[wa][0] + red[wb][0];
        float sfw = red[wa][1] + red[wb][1];
        float inv = rsqrtf(sff);
        float d2 = sff * inv * inv + sqw[tgt] - 2.f * inv * sfw;
        d2 = fmaxf(d2, 0.f);
        float dist = sqrtf(d2);
        atomicAdd(class_sum + tgt, dist);
        atomicAdd(class_cnt + tgt, 1.f);
    }
}

// --- finalize both scalars ---
__global__ __launch_bounds__(256) void kfin(const float* __restrict__ class_sum,
                                            const float* __restrict__ class_cnt,
                                            const float* __restrict__ pair_acc,
                                            float* __restrict__ out) {
    float msum = 0.f, pcnt = 0.f;
    for (int c = threadIdx.x; c < CC; c += 256) {
        float cnt = class_cnt[c];
        if (cnt > 0.f) {
            msum += class_sum[c] / cnt;
            pcnt += 1.f;
        }
    }
    msum = wave_reduce(msum);
    pcnt = wave_reduce(pcnt);
    __shared__ float rs[4], rc[4];
    int wv = threadIdx.x >> 6;
    if ((threadIdx.x & 63) == 0) { rs[wv] = msum; rc[wv] = pcnt; }
    __syncthreads();
    if (threadIdx.x == 0) {
        float sm = rs[0] + rs[1] + rs[2] + rs[3];
        float sp = rc[0] + rc[1] + rc[2] + rc[3];
        out[0] = 1.0f * (sm / sp);                      // BETA * sample_wise
        out[1] = 1.0f * (pair_acc[0] / pair_acc[1]);    // ALPHA * weight_wise
    }
}

extern "C" void kernel_launch(void* const* d_in, const int* in_sizes, int n_in,
                              void* d_out, int out_size, void* d_ws, size_t ws_size,
                              hipStream_t stream) {
    const float* feat = (const float*)d_in[0];
    const float* cls = (const float*)d_in[1];
    const int* target = (const int*)d_in[2];
    float* out = (float*)d_out;
    float* ws = (float*)d_ws;

    float* w = ws;
    float* sqw = ws + 512000;
    float* class_sum = ws + 513000;
    float* class_cnt = ws + 514000;
    float* pair_acc = ws + 515000;

    // zero accumulators (class_sum, class_cnt, pair_acc are contiguous)
    hipMemsetAsync(class_sum, 0, (2 * CC + 2) * sizeof(float), stream);

    knorm<<<CC, 64, 0, stream>>>(cls, w, sqw);
    kpair<<<dim3((CC + TILE - 1) / TILE, (CC + TILE - 1) / TILE), 256, 0, stream>>>(w, sqw, pair_acc);
    ksample<<<NN / 2, 256, 0, stream>>>(feat, target, w, sqw, class_sum, class_cnt, out + 2);
    kfin<<<1, 256, 0, stream>>>(class_sum, class_cnt, pair_acc, out);
}